// Round 1
// baseline (27592.923 us; speedup 1.0000x reference)
//
#include <hip/hip_runtime.h>

#define Bsz 1024
#define Ssz 512
#define Hsz 512
#define G3  1536
#define H2  256
#define BT  16
#define WGS 1024

typedef __attribute__((ext_vector_type(8))) short short8;
typedef __attribute__((ext_vector_type(4))) float f32x4;

__device__ __forceinline__ unsigned short f2bf(float f) {
  unsigned int u = __builtin_bit_cast(unsigned int, f);
  u += 0x7fffu + ((u >> 16) & 1u);   // RNE (finite inputs)
  return (unsigned short)(u >> 16);
}

__device__ __forceinline__ float sigm(float x) {
  x = fminf(fmaxf(x, -30.f), 30.f);
  return 1.f / (1.f + __expf(-x));
}
__device__ __forceinline__ float tanh_f(float x) {
  x = fminf(fmaxf(x, -15.f), 15.f);
  float e = __expf(2.f * x);
  return (e - 1.f) / (e + 1.f);
}

// Pack W_hh [1536,512] f32 -> fragment-ordered bf16.
// Layout: byte offset (((w*6+tt)*16+kk)*64+l)*16 ; tt = gate*2+th
// holds W_hh[gate*512 + w*32 + th*16 + (l&15)][kk*32 + (l>>4)*8 + e], e=0..7
__global__ void pack_whh_k(const float* __restrict__ Wp, unsigned short* __restrict__ dst) {
  int T = blockIdx.x * 256 + threadIdx.x;      // 98304 threads
  int l  = T & 63;
  int r1 = T >> 6;
  int kk = r1 & 15;
  int r2 = r1 >> 4;
  int tt = r2 % 6;
  int w  = r2 / 6;
  int g = tt >> 1, th = tt & 1;
  int j  = g * 512 + w * 32 + th * 16 + (l & 15);
  int kb = kk * 32 + (l >> 4) * 8;
  const float* src = Wp + j * 512 + kb;
  short8 o;
#pragma unroll
  for (int e = 0; e < 8; ++e) o[e] = (short)f2bf(src[e]);
  *reinterpret_cast<short8*>(dst + (size_t)T * 8) = o;
}

// Pack W1 [256,512] f32 -> fragment-ordered bf16.
// byte offset ((w*16+kk)*64+l)*16 holds W1[w*16+(l&15)][kk*32+(l>>4)*8+e]
__global__ void pack_w1_k(const float* __restrict__ W1, unsigned short* __restrict__ dst) {
  int T = blockIdx.x * 256 + threadIdx.x;      // 16384 threads
  int l  = T & 63;
  int r1 = T >> 6;
  int kk = r1 & 15;
  int w  = r1 >> 4;
  int j  = w * 16 + (l & 15);
  int kb = kk * 32 + (l >> 4) * 8;
  const float* src = W1 + j * 512 + kb;
  short8 o;
#pragma unroll
  for (int e = 0; e < 8; ++e) o[e] = (short)f2bf(src[e]);
  *reinterpret_cast<short8*>(dst + (size_t)T * 8) = o;
}

// One WG per 16-row batch tile; 16 waves; wave w owns h-cols [w*32, w*32+32)
// (3 gates x 2 col-tiles of 16) + MLP cols [w*16, w*16+16).
__global__ __launch_bounds__(1024) void gru_main(
    const float* __restrict__ X0, const float* __restrict__ V,
    const float* __restrict__ Wih, const float* __restrict__ bih_g,
    const float* __restrict__ bhh_g, const float* __restrict__ b1_g,
    const float* __restrict__ W2_g, const float* __restrict__ b2_g,
    const unsigned short* __restrict__ PW, const unsigned short* __restrict__ PW1,
    float* __restrict__ out)
{
  __shared__ alignas(16) float h32[BT][Hsz];            // 32 KB fp32 master
  __shared__ alignas(16) unsigned short hb[BT * Hsz];   // 16 KB bf16 mirror (XOR-swizzled 16B slots)
  __shared__ float bihs[G3];
  __shared__ float bhhs[G3];
  __shared__ alignas(16) float gin[BT][4];              // [v0,v1,x0,x1] per row
  __shared__ float xprev[BT][2];
  __shared__ float part[16][BT][2];

  const int tid = threadIdx.x;
  const int l   = tid & 63;
  const int w   = tid >> 6;
  const int lm  = l & 15;
  const int ld  = l >> 4;
  const int row0 = blockIdx.x * BT;

  for (int i = tid; i < G3; i += WGS) { bihs[i] = bih_g[i]; bhhs[i] = bhh_g[i]; }
  for (int i = tid; i < BT * Hsz; i += WGS) hb[i] = 0;
  for (int i = tid; i < BT * Hsz; i += WGS) h32[i >> 9][i & 511] = 0.f;
  if (tid < BT * 2) {
    int m = tid >> 1, c = tid & 1;
    float x0 = X0[(row0 + m) * 2 + c];
    xprev[m][c]   = x0;
    gin[m][2 + c] = x0;
    gin[m][c]     = V[(size_t)(row0 + m) * (Ssz * 2) + c];   // v_0
  }
  __syncthreads();

  const char* hbB  = reinterpret_cast<const char*>(hb);
  char*       hbW  = reinterpret_cast<char*>(hb);
  const char* pwB  = reinterpret_cast<const char*>(PW)  + (size_t)w * (6 * 16 * 1024);
  const char* pw1B = reinterpret_cast<const char*>(PW1) + (size_t)w * (16 * 1024);
  const int abase = lm * 1024 + ld * 16;       // A-frag: row lm, k-group ld
  const int aswz  = (lm & 7) << 4;
  const int jh0   = w * 32;
  const f32x4* Wih4 = reinterpret_cast<const f32x4*>(Wih);

  for (int t = 0; t < Ssz; ++t) {
    // ---- gh GEMM: acc[g*2+th] = h_{t-1} @ W_hh^T (tile) ----
    f32x4 acc[6];
#pragma unroll
    for (int q = 0; q < 6; ++q) acc[q] = (f32x4){0.f, 0.f, 0.f, 0.f};

    for (int kk = 0; kk < 16; ++kk) {
      short8 a = *reinterpret_cast<const short8*>(hbB + ((abase + kk * 64) ^ aswz));
      const char* p = pwB + kk * 1024 + l * 16;
#pragma unroll
      for (int q = 0; q < 6; ++q) {
        short8 b = *reinterpret_cast<const short8*>(p + q * 16 * 1024);
        acc[q] = __builtin_amdgcn_mfma_f32_16x16x32_bf16(a, b, acc[q], 0, 0, 0);
      }
    }
    __syncthreads();   // all waves done reading h_{t-1} mirror

    // ---- gates + h update (writes h_t) ----
#pragma unroll
    for (int th = 0; th < 2; ++th) {
      const int jh = jh0 + th * 16 + lm;
      const f32x4 wr = Wih4[jh];
      const f32x4 wz = Wih4[512 + jh];
      const f32x4 wn = Wih4[1024 + jh];
      const float bir = bihs[jh],        bhr = bhhs[jh];
      const float biz = bihs[512 + jh],  bhz = bhhs[512 + jh];
      const float bin = bihs[1024 + jh], bhn = bhhs[1024 + jh];
#pragma unroll
      for (int r = 0; r < 4; ++r) {
        const int m = ld * 4 + r;
        const f32x4 g4 = *reinterpret_cast<const f32x4*>(&gin[m][0]);
        float gr = wr[0]*g4[0] + wr[1]*g4[1] + wr[2]*g4[2] + wr[3]*g4[3] + bir
                 + acc[0 * 2 + th][r] + bhr;
        float gz = wz[0]*g4[0] + wz[1]*g4[1] + wz[2]*g4[2] + wz[3]*g4[3] + biz
                 + acc[1 * 2 + th][r] + bhz;
        float hn = acc[2 * 2 + th][r] + bhn;
        float gn = wn[0]*g4[0] + wn[1]*g4[1] + wn[2]*g4[2] + wn[3]*g4[3] + bin;
        float rr = sigm(gr);
        float zz = sigm(gz);
        float nn = tanh_f(gn + rr * hn);
        float hp = h32[m][jh];
        float ht = (1.f - zz) * nn + zz * hp;
        h32[m][jh] = ht;
        *reinterpret_cast<unsigned short*>(hbW + ((m * 1024 + jh * 2) ^ ((m & 7) << 4)))
            = f2bf(ht);
      }
    }
    __syncthreads();   // h_t ready

    // ---- residual MLP: m = relu(h_t @ W1^T + b1); res = m @ W2^T ----
    f32x4 am = (f32x4){0.f, 0.f, 0.f, 0.f};
    for (int kk = 0; kk < 16; ++kk) {
      short8 a = *reinterpret_cast<const short8*>(hbB + ((abase + kk * 64) ^ aswz));
      short8 b = *reinterpret_cast<const short8*>(pw1B + kk * 1024 + l * 16);
      am = __builtin_amdgcn_mfma_f32_16x16x32_bf16(a, b, am, 0, 0, 0);
    }
    const int ic = w * 16 + lm;
    const float b1v = b1_g[ic];
    const float w2a = W2_g[ic];          // W2[0][ic]
    const float w2b = W2_g[256 + ic];    // W2[1][ic]
    float pa[4], pb[4];
#pragma unroll
    for (int r = 0; r < 4; ++r) {
      float mv = fmaxf(am[r] + b1v, 0.f);
      pa[r] = mv * w2a;
      pb[r] = mv * w2b;
    }
#pragma unroll
    for (int off = 1; off < 16; off <<= 1) {
#pragma unroll
      for (int r = 0; r < 4; ++r) {
        pa[r] += __shfl_xor(pa[r], off);
        pb[r] += __shfl_xor(pb[r], off);
      }
    }
    if (lm == 0) {
#pragma unroll
      for (int r = 0; r < 4; ++r) {
        part[w][ld * 4 + r][0] = pa[r];
        part[w][ld * 4 + r][1] = pb[r];
      }
    }
    __syncthreads();   // partials ready

    // ---- finisher: x_t = x_{t-1} + v_t + res; stage next step's inputs ----
    if (tid < 32) {
      int m = tid >> 1, c = tid & 1;
      float s = b2_g[c];
#pragma unroll
      for (int ww = 0; ww < 16; ++ww) s += part[ww][m][c];
      float vt = gin[m][c];
      float xt = xprev[m][c] + vt + s;
      out[(size_t)(row0 + m) * (Ssz * 2) + t * 2 + c] = xt;
      xprev[m][c]   = xt;
      gin[m][2 + c] = xt;
      gin[m][c] = (t + 1 < Ssz) ? V[(size_t)(row0 + m) * (Ssz * 2) + (t + 1) * 2 + c] : 0.f;
    }
    // no barrier needed here: next GEMM touches only hb/PW; gate phase (the
    // first gin/xprev reader) is after the next post-GEMM barrier.
  }
}

extern "C" void kernel_launch(void* const* d_in, const int* in_sizes, int n_in,
                              void* d_out, int out_size, void* d_ws, size_t ws_size,
                              hipStream_t stream) {
  const float* X0  = (const float*)d_in[0];
  const float* V   = (const float*)d_in[1];
  const float* Wih = (const float*)d_in[2];
  const float* Whh = (const float*)d_in[3];
  const float* bih = (const float*)d_in[4];
  const float* bhh = (const float*)d_in[5];
  const float* W1  = (const float*)d_in[6];
  const float* b1  = (const float*)d_in[7];
  const float* W2  = (const float*)d_in[8];
  const float* b2  = (const float*)d_in[9];
  float* out = (float*)d_out;

  // workspace: packed bf16 weights (1.5 MB + 0.25 MB)
  unsigned short* PW  = (unsigned short*)d_ws;
  unsigned short* PW1 = PW + (size_t)G3 * Hsz;

  pack_whh_k<<<384, 256, 0, stream>>>(Whh, PW);
  pack_w1_k<<<64, 256, 0, stream>>>(W1, PW1);
  gru_main<<<64, 1024, 0, stream>>>(X0, V, Wih, bih, bhh, b1, W2, b2, PW, PW1, out);
}